// Round 1
// baseline (264.622 us; speedup 1.0000x reference)
//
#include <hip/hip_runtime.h>

// out = 2*tangents_1 + (N-1)*full_default, elementwise over N*ROWS*COLS fp32.
// N=100, ROWS=2048, COLS=512 -> 104,857,600 elements, divisible by 4.
// Purely HBM-bound: 1.258 GB total traffic -> ~200 us floor at 6.3 TB/s.

__global__ __launch_bounds__(256) void fused_axpby_kernel(
    const float4* __restrict__ fd,
    const float4* __restrict__ tg,
    float4* __restrict__ out,
    long n4)
{
    long i = (long)blockIdx.x * blockDim.x + threadIdx.x;
    const long stride = (long)gridDim.x * blockDim.x;
    for (; i < n4; i += stride) {
        float4 a = fd[i];
        float4 b = tg[i];
        float4 r;
        r.x = 2.0f * b.x + 99.0f * a.x;
        r.y = 2.0f * b.y + 99.0f * a.y;
        r.z = 2.0f * b.z + 99.0f * a.z;
        r.w = 2.0f * b.w + 99.0f * a.w;
        out[i] = r;
    }
}

extern "C" void kernel_launch(void* const* d_in, const int* in_sizes, int n_in,
                              void* d_out, int out_size, void* d_ws, size_t ws_size,
                              hipStream_t stream)
{
    const float4* fd = (const float4*)d_in[0];   // full_default
    const float4* tg = (const float4*)d_in[1];   // tangents_1
    float4* out = (float4*)d_out;

    const long n = (long)out_size;   // 104,857,600
    const long n4 = n / 4;           // 26,214,400 (exact)

    const int block = 256;
    // Memory-bound: cap grid at ~8 blocks/CU * 256 CU and grid-stride.
    long blocks_needed = (n4 + block - 1) / block;
    int grid = (int)(blocks_needed < 2048 ? blocks_needed : 2048);

    fused_axpby_kernel<<<grid, block, 0, stream>>>(fd, tg, out, n4);
}

// Round 3
// 236.639 us; speedup vs baseline: 1.1183x; 1.1183x over previous
//
#include <hip/hip_runtime.h>

// out = 2*tangents_1 + 99*full_default, elementwise over 104,857,600 fp32.
// HBM-bound. R1: 2.9 TB/s HBM-only, VALUBusy 2.2% -> latency-limited.
// Fix: 4x unroll (8 independent 16B loads in flight per thread) + nontemporal
// stores (keep 419 MB write stream out of L3; R1 showed L3 absorbing ~420 MB
// of the reads -- protect that).
// NOTE: __builtin_nontemporal_store requires a native clang vector type,
// not HIP's float4 class (R2 compile failure).

typedef float v4f __attribute__((ext_vector_type(4)));

constexpr int BLOCK = 256;
constexpr int ITEMS = 4;                      // v4f per thread per chunk
constexpr long CHUNK = (long)BLOCK * ITEMS;   // 1024 v4f per block-chunk

__global__ __launch_bounds__(BLOCK) void fused_axpby_kernel(
    const v4f* __restrict__ fd,
    const v4f* __restrict__ tg,
    v4f* __restrict__ out,
    long n4)
{
    const long nchunks = n4 / CHUNK;          // full chunks
    const long stride = (long)gridDim.x * CHUNK;
    long base = (long)blockIdx.x * CHUNK + threadIdx.x;

    for (long c = blockIdx.x; c < nchunks; c += gridDim.x, base += stride) {
        // 8 independent coalesced loads issued back-to-back
        v4f a0 = fd[base + 0 * BLOCK];
        v4f a1 = fd[base + 1 * BLOCK];
        v4f a2 = fd[base + 2 * BLOCK];
        v4f a3 = fd[base + 3 * BLOCK];
        v4f b0 = tg[base + 0 * BLOCK];
        v4f b1 = tg[base + 1 * BLOCK];
        v4f b2 = tg[base + 2 * BLOCK];
        v4f b3 = tg[base + 3 * BLOCK];

        v4f r0 = 2.0f * b0 + 99.0f * a0;
        v4f r1 = 2.0f * b1 + 99.0f * a1;
        v4f r2 = 2.0f * b2 + 99.0f * a2;
        v4f r3 = 2.0f * b3 + 99.0f * a3;

        __builtin_nontemporal_store(r0, &out[base + 0 * BLOCK]);
        __builtin_nontemporal_store(r1, &out[base + 1 * BLOCK]);
        __builtin_nontemporal_store(r2, &out[base + 2 * BLOCK]);
        __builtin_nontemporal_store(r3, &out[base + 3 * BLOCK]);
    }

    // tail (n4 % CHUNK) -- zero for this problem size, kept for safety
    const long tail_start = nchunks * CHUNK;
    for (long i = tail_start + (long)blockIdx.x * BLOCK + threadIdx.x;
         i < n4; i += (long)gridDim.x * BLOCK) {
        v4f a = fd[i];
        v4f b = tg[i];
        v4f r = 2.0f * b + 99.0f * a;
        __builtin_nontemporal_store(r, &out[i]);
    }
}

extern "C" void kernel_launch(void* const* d_in, const int* in_sizes, int n_in,
                              void* d_out, int out_size, void* d_ws, size_t ws_size,
                              hipStream_t stream)
{
    const v4f* fd = (const v4f*)d_in[0];   // full_default
    const v4f* tg = (const v4f*)d_in[1];   // tangents_1
    v4f* out = (v4f*)d_out;

    const long n = (long)out_size;   // 104,857,600
    const long n4 = n / 4;           // 26,214,400

    long nchunks = (n4 + CHUNK - 1) / CHUNK;     // 25,600
    int grid = (int)(nchunks < 2048 ? nchunks : 2048);

    fused_axpby_kernel<<<grid, BLOCK, 0, stream>>>(fd, tg, out, n4);
}

// Round 4
// 221.451 us; speedup vs baseline: 1.1949x; 1.0686x over previous
//
#include <hip/hip_runtime.h>

// out = 2*tangents_1 + 99*full_default, elementwise over 104,857,600 fp32.
// HBM-bound streaming op. R3: 237 us = 5.3 TB/s demand BW (84% of 6.3 TB/s
// practical ceiling). This round: drop the grid-stride loop -- one chunk per
// block (25,600 blocks x 1024 float4, exact fit, zero tail), minimal index
// math. nt stores kept (write stream bypasses L3, preserving the measured
// 419 MB read absorption).
// NOTE: __builtin_nontemporal_store needs a native clang vector type.

typedef float v4f __attribute__((ext_vector_type(4)));

constexpr int BLOCK = 256;
constexpr int ITEMS = 4;                      // v4f per thread
constexpr int CHUNK = BLOCK * ITEMS;          // 1024 v4f per block

__global__ __launch_bounds__(BLOCK) void fused_axpby_kernel(
    const v4f* __restrict__ fd,
    const v4f* __restrict__ tg,
    v4f* __restrict__ out)
{
    // 25,600 * 1024 = 26,214,400 v4f = full problem, no bounds checks needed.
    const long base = (long)blockIdx.x * CHUNK + threadIdx.x;

    v4f a0 = fd[base + 0 * BLOCK];
    v4f a1 = fd[base + 1 * BLOCK];
    v4f a2 = fd[base + 2 * BLOCK];
    v4f a3 = fd[base + 3 * BLOCK];
    v4f b0 = tg[base + 0 * BLOCK];
    v4f b1 = tg[base + 1 * BLOCK];
    v4f b2 = tg[base + 2 * BLOCK];
    v4f b3 = tg[base + 3 * BLOCK];

    v4f r0 = 2.0f * b0 + 99.0f * a0;
    v4f r1 = 2.0f * b1 + 99.0f * a1;
    v4f r2 = 2.0f * b2 + 99.0f * a2;
    v4f r3 = 2.0f * b3 + 99.0f * a3;

    __builtin_nontemporal_store(r0, &out[base + 0 * BLOCK]);
    __builtin_nontemporal_store(r1, &out[base + 1 * BLOCK]);
    __builtin_nontemporal_store(r2, &out[base + 2 * BLOCK]);
    __builtin_nontemporal_store(r3, &out[base + 3 * BLOCK]);
}

extern "C" void kernel_launch(void* const* d_in, const int* in_sizes, int n_in,
                              void* d_out, int out_size, void* d_ws, size_t ws_size,
                              hipStream_t stream)
{
    const v4f* fd = (const v4f*)d_in[0];   // full_default
    const v4f* tg = (const v4f*)d_in[1];   // tangents_1
    v4f* out = (v4f*)d_out;

    const long n4 = (long)out_size / 4;    // 26,214,400
    const int grid = (int)(n4 / CHUNK);    // 25,600 exactly

    fused_axpby_kernel<<<grid, BLOCK, 0, stream>>>(fd, tg, out);
}